// Round 15
// baseline (95.295 us; speedup 1.0000x reference)
//
#include <hip/hip_runtime.h>

// 5-level Db4 DWT, rows of 16384 fp32, B*C = 4096 rows.
// r12 structure (quarter-split rows, telescoping halos a1:120/a2:56/a3:24/a4:8,
// x staged via global_load_lds w=16 with pre-swizzled source, XOR-swizzled LDS,
// LDS-only barriers, builtin NT stores) with L1/L2 widened to 8 outputs per
// thread (24-float window: 6 b128 reads per 2 b128 written -> 25% less LDS
// read traffic, ~40% fewer instructions in the heavy phases).
// out layout (flat, return order):
//   Fd  4096x512   @ 0
//   Ft  4096x512   @ 2097152
//   Fa  4096x1024  @ 4194304
//   Fb  4096x2048  @ 8388608
//   Fg  4096x4096  @ 16777216
//   FR  4096x8192  @ 33554432   (per-row: [Fd|Ft|Fa|Fb|Fg])

static constexpr int SLEN = 16384;

typedef float f32x4 __attribute__((ext_vector_type(4)));

// Swizzled float offset for a float4-aligned region-relative offset f (>=0).
__device__ __forceinline__ int swz4(int f) {
    const int s = f >> 2;
    return (s ^ ((s >> 3) & 7)) << 2;
}
__device__ __forceinline__ int swz1(int f) {
    const int s = f >> 2;
    return (((s ^ ((s >> 3) & 7)) << 2) | (f & 3));
}

// Db4 filters are fixed (non-learnable) — hardcoded as literals.
__device__ __forceinline__ float dotH(const float* w) {
    float s =      -0.010597401785069032f * w[0];
    s = fmaf( 0.032883011666982945f, w[1], s);
    s = fmaf( 0.030841381835560764f, w[2], s);
    s = fmaf(-0.18703481171888114f,  w[3], s);
    s = fmaf(-0.02798376941698385f,  w[4], s);
    s = fmaf( 0.6308807679295904f,   w[5], s);
    s = fmaf( 0.7148465705529155f,   w[6], s);
    s = fmaf( 0.2303778133088964f,   w[7], s);
    return s;
}
// g[k] = (-1)^k * h[7-k]
__device__ __forceinline__ float dotG(const float* w) {
    float s =       0.2303778133088964f * w[0];
    s = fmaf(-0.7148465705529155f,   w[1], s);
    s = fmaf( 0.6308807679295904f,   w[2], s);
    s = fmaf( 0.02798376941698385f,  w[3], s);
    s = fmaf(-0.18703481171888114f,  w[4], s);
    s = fmaf(-0.030841381835560764f, w[5], s);
    s = fmaf( 0.032883011666982945f, w[6], s);
    s = fmaf( 0.010597401785069032f, w[7], s);
    return s;
}

// SWIZZLED LDS window loads.
__device__ __forceinline__ void lw16s(const float* __restrict__ base, int foff, float* w) {
#pragma unroll
    for (int j = 0; j < 4; ++j) {
        const float4 v = *(const float4*)(base + swz4(foff + 4 * j));
        w[4*j+0] = v.x; w[4*j+1] = v.y; w[4*j+2] = v.z; w[4*j+3] = v.w;
    }
}
__device__ __forceinline__ void lw16s_q0(const float* __restrict__ base, float* w) {
#pragma unroll
    for (int i = 0; i < 16; ++i) { int m = i - 8; m = (m < 0) ? -m : m; w[i] = base[swz1(m)]; }
}
// 24-float window (8-output groups).
__device__ __forceinline__ void lw24s(const float* __restrict__ base, int foff, float* w) {
#pragma unroll
    for (int j = 0; j < 6; ++j) {
        const float4 v = *(const float4*)(base + swz4(foff + 4 * j));
        w[4*j+0] = v.x; w[4*j+1] = v.y; w[4*j+2] = v.z; w[4*j+3] = v.w;
    }
}
__device__ __forceinline__ void lw24s_q0(const float* __restrict__ base, float* w) {
#pragma unroll
    for (int i = 0; i < 24; ++i) { int m = i - 8; m = (m < 0) ? -m : m; w[i] = base[swz1(m)]; }
}

// NT store (builtin — correct vmcnt bookkeeping; +20% vs cached, r9/r11 A/B).
__device__ __forceinline__ void ntst4(float* p, float a0, float a1, float a2, float a3) {
    f32x4 v; v.x = a0; v.y = a1; v.z = a2; v.w = a3;
    __builtin_nontemporal_store(v, (f32x4*)p);
}

// Async global->LDS, 16B per lane.
__device__ __forceinline__ void gl_lds16(const float* gp, float* lp) {
    __builtin_amdgcn_global_load_lds(
        (const __attribute__((address_space(1))) void*)gp,
        (__attribute__((address_space(3))) void*)lp, 16, 0, 0);
}

// Barrier that waits on LDS ops only; outstanding NT stores drain in background.
__device__ __forceinline__ void barrier_lds() {
    asm volatile("s_waitcnt lgkmcnt(0)" ::: "memory");
    __builtin_amdgcn_s_barrier();
    asm volatile("" ::: "memory");
}

__global__ __launch_bounds__(256, 6)
void dwt5_kernel(const float* __restrict__ x, float* __restrict__ out)
{
    // Region map (floats; bases multiples of 32 floats):
    //   xs: buf+0    [0 .. 4352)  staged x (linear dest, pre-swizzled source)
    //   a1: buf+4352 [0 .. 2176)
    //   a2: buf+0    [0 .. 1088)  (xs dead after L1 barrier)
    //   a3: buf+2048 [0 .. 544)
    //   a4: buf+3072 [0 .. 272)
    __shared__ float buf[6528];   // 25.5 KB -> 6 blocks/CU
    const int bid = blockIdx.x;
    const int r   = bid >> 2;     // row
    const int h   = bid & 3;      // quarter
    const int tid = threadIdx.x;

    const float* __restrict__ xr = x + (size_t)r * SLEN;
    const size_t frBase = (size_t)33554432 + (size_t)r * 8192;

    // Region shift per level (quarter h=0 has no halo).
    const int X0  = h ? 4096*h - 256 : 0;
    const int A1s = h ? 2048*h - 120 : 0;   // = 8*(256h-15)
    const int A2s = h ? 1024*h - 56  : 0;   // = 8*(128h-7)
    const int A3s = h ?  512*h - 24  : 0;
    const int A4s = h ?  256*h - 8   : 0;
    constexpr int RA1 = 4352;
    constexpr int RA2 = 0;
    constexpr int RA3 = 2048;
    constexpr int RA4 = 3072;

    // ---- STAGE: x -> xs (linear LDS; source pre-swizzled so reads can swz) ----
    {
        const float* xsrc = xr + X0;
#pragma unroll
        for (int j = 0; j < 4; ++j) {
            const int L  = tid + 256*j;
            const int Ls = L ^ ((L >> 3) & 7);
            gl_lds16(xsrc + 4*Ls, buf + 4*L);
        }
        if (h != 0 && tid < 64) {              // slots 1024..1087 (halo)
            const int L  = tid + 1024;
            const int Ls = L ^ ((L >> 3) & 7);
            gl_lds16(xsrc + 4*Ls, buf + 4*L);
        }
        asm volatile("s_waitcnt vmcnt(0)" ::: "memory");
    }
    barrier_lds();

    // ---- L1: xs -> a1 (low only; d1 never output), 8 outputs/thread ----
    {
        const int q1lo = A1s >> 3;            // 256h-15 | 0
        const int q1hi = 256 * (h + 1);
#pragma unroll
        for (int jj = 0; jj < 2; ++jj) {
            const int q = q1lo + tid + jj * 256;
            if (q < q1hi) {
                float w[24];
                if (q == 0) lw24s_q0(buf, w);
                else        lw24s(buf, 16 * q - 8 - X0, w);
                float a[8];
#pragma unroll
                for (int t = 0; t < 8; ++t) a[t] = dotH(w + 2*t + 1);
                *(float4*)(buf + RA1 + swz4(8 * q     - A1s)) = make_float4(a[0], a[1], a[2], a[3]);
                *(float4*)(buf + RA1 + swz4(8 * q + 4 - A1s)) = make_float4(a[4], a[5], a[6], a[7]);
            }
        }
    }
    barrier_lds();

    // ---- L2: a1 -> a2, d2 -> Fg + FR, 8 outputs/thread ----
    {
        const int q2lo = A2s >> 3;            // 128h-7 | 0
        const int q2hi = 128 * (h + 1);
        const int dd   = 128 * h;
        float* __restrict__ hi1 = out + (size_t)16777216 + (size_t)r * 4096;
        float* __restrict__ hi2 = out + frBase + 4096;
        const int q = q2lo + tid;             // max count 135 <= 256, one iter
        if (q < q2hi) {
            float w[24];
            if (q == 0) lw24s_q0(buf + RA1, w);
            else        lw24s(buf + RA1, 16 * q - 8 - A1s, w);
            float a[8];
#pragma unroll
            for (int t = 0; t < 8; ++t) a[t] = dotH(w + 2*t + 1);
            *(float4*)(buf + RA2 + swz4(8 * q     - A2s)) = make_float4(a[0], a[1], a[2], a[3]);
            *(float4*)(buf + RA2 + swz4(8 * q + 4 - A2s)) = make_float4(a[4], a[5], a[6], a[7]);
            if (q >= dd) {
                float d[8];
#pragma unroll
                for (int t = 0; t < 8; ++t) d[t] = dotG(w + 2*t + 1);
                ntst4(hi1 + 8 * q,     d[0], d[1], d[2], d[3]);
                ntst4(hi1 + 8 * q + 4, d[4], d[5], d[6], d[7]);
                ntst4(hi2 + 8 * q,     d[0], d[1], d[2], d[3]);
                ntst4(hi2 + 8 * q + 4, d[4], d[5], d[6], d[7]);
            }
        }
    }
    barrier_lds();

    // ---- L3: a2 -> a3, d3 -> Fb + FR ----
    {
        const int g3lo = A3s >> 2;            // 128h-6 | 0
        const int g3hi = 128 * (h + 1);
        const int gd   = 128 * h;
        float* __restrict__ hi1 = out + (size_t)8388608 + (size_t)r * 2048;
        float* __restrict__ hi2 = out + frBase + 2048;
        const int g = g3lo + tid;
        if (g < g3hi) {
            float w[16];
            if (g == 0) lw16s_q0(buf + RA2, w);
            else        lw16s(buf + RA2, 8 * g - 8 - A2s, w);
            const float a0 = dotH(w + 1), a1 = dotH(w + 3), a2 = dotH(w + 5), a3 = dotH(w + 7);
            *(float4*)(buf + RA3 + swz4(4 * g - A3s)) = make_float4(a0, a1, a2, a3);
            if (g >= gd) {
                const float d0 = dotG(w + 1), d1 = dotG(w + 3), d2 = dotG(w + 5), d3 = dotG(w + 7);
                ntst4(hi1 + 4 * g, d0, d1, d2, d3);
                ntst4(hi2 + 4 * g, d0, d1, d2, d3);
            }
        }
    }
    barrier_lds();

    // ---- L4: a3 -> a4, d4 -> Fa + FR ----
    {
        const int g4lo = A4s >> 2;            // 64h-2 | 0
        const int g4hi = 64 * (h + 1);
        const int gd   = 64 * h;
        float* __restrict__ hi1 = out + (size_t)4194304 + (size_t)r * 1024;
        float* __restrict__ hi2 = out + frBase + 1024;
        const int g = g4lo + tid;
        if (g < g4hi) {
            float w[16];
            if (g == 0) lw16s_q0(buf + RA3, w);
            else        lw16s(buf + RA3, 8 * g - 8 - A3s, w);
            const float a0 = dotH(w + 1), a1 = dotH(w + 3), a2 = dotH(w + 5), a3 = dotH(w + 7);
            *(float4*)(buf + RA4 + swz4(4 * g - A4s)) = make_float4(a0, a1, a2, a3);
            if (g >= gd) {
                const float d0 = dotG(w + 1), d1 = dotG(w + 3), d2 = dotG(w + 5), d3 = dotG(w + 7);
                ntst4(hi1 + 4 * g, d0, d1, d2, d3);
                ntst4(hi2 + 4 * g, d0, d1, d2, d3);
            }
        }
    }
    barrier_lds();

    // ---- L5: a4 -> Fd + Ft, both also to FR ----
    if (tid < 32) {
        const int g = 32 * h + tid;
        float w[16];
        if (g == 0) lw16s_q0(buf + RA4, w);
        else        lw16s(buf + RA4, 8 * g - 8 - A4s, w);
        const float a0 = dotH(w + 1), a1 = dotH(w + 3), a2 = dotH(w + 5), a3 = dotH(w + 7);
        const float d0 = dotG(w + 1), d1 = dotG(w + 3), d2 = dotG(w + 5), d3 = dotG(w + 7);
        ntst4(out + (size_t)r * 512 + 4 * g,                   a0, a1, a2, a3);
        ntst4(out + frBase + 4 * g,                            a0, a1, a2, a3);
        ntst4(out + (size_t)2097152 + (size_t)r * 512 + 4 * g, d0, d1, d2, d3);
        ntst4(out + frBase + 512 + 4 * g,                      d0, d1, d2, d3);
    }
}

extern "C" void kernel_launch(void* const* d_in, const int* in_sizes, int n_in,
                              void* d_out, int out_size, void* d_ws, size_t ws_size,
                              hipStream_t stream) {
    const float* x = (const float*)d_in[0];
    float* out = (float*)d_out;
    dwt5_kernel<<<16384, 256, 0, stream>>>(x, out);
}

// Round 16
// 91.012 us; speedup vs baseline: 1.0471x; 1.0471x over previous
//
#include <hip/hip_runtime.h>

// 5-level Db4 DWT, rows of 16384 fp32, B*C = 4096 rows.
// r9 cascade structure (quarter-split rows, telescoping halos a1:120/a2:56/
// a3:24/a4:8, XOR-swizzled LDS, LDS-only barriers, builtin NT stores) but
// TWO ROWS PER BLOCK: each phase does row0 then row1 between the same
// barriers -> 2x independent work per barrier (ILP), half the total
// barrier-waits. LDS 2 x 13.1 KB = 26.1 KB -> 6 blocks/CU.
// out layout (flat, return order):
//   Fd  4096x512   @ 0
//   Ft  4096x512   @ 2097152
//   Fa  4096x1024  @ 4194304
//   Fb  4096x2048  @ 8388608
//   Fg  4096x4096  @ 16777216
//   FR  4096x8192  @ 33554432   (per-row: [Fd|Ft|Fa|Fb|Fg])

static constexpr int SLEN = 16384;

typedef float f32x4 __attribute__((ext_vector_type(4)));

// Swizzled float offset for a float4-aligned region-relative offset f (>=0).
__device__ __forceinline__ int swz4(int f) {
    const int s = f >> 2;
    return (s ^ ((s >> 3) & 7)) << 2;
}
__device__ __forceinline__ int swz1(int f) {
    const int s = f >> 2;
    return (((s ^ ((s >> 3) & 7)) << 2) | (f & 3));
}

// Db4 filters are fixed (non-learnable) — hardcoded as literals.
__device__ __forceinline__ float dotH(const float* w) {
    float s =      -0.010597401785069032f * w[0];
    s = fmaf( 0.032883011666982945f, w[1], s);
    s = fmaf( 0.030841381835560764f, w[2], s);
    s = fmaf(-0.18703481171888114f,  w[3], s);
    s = fmaf(-0.02798376941698385f,  w[4], s);
    s = fmaf( 0.6308807679295904f,   w[5], s);
    s = fmaf( 0.7148465705529155f,   w[6], s);
    s = fmaf( 0.2303778133088964f,   w[7], s);
    return s;
}
// g[k] = (-1)^k * h[7-k]
__device__ __forceinline__ float dotG(const float* w) {
    float s =       0.2303778133088964f * w[0];
    s = fmaf(-0.7148465705529155f,   w[1], s);
    s = fmaf( 0.6308807679295904f,   w[2], s);
    s = fmaf( 0.02798376941698385f,  w[3], s);
    s = fmaf(-0.18703481171888114f,  w[4], s);
    s = fmaf(-0.030841381835560764f, w[5], s);
    s = fmaf( 0.032883011666982945f, w[6], s);
    s = fmaf( 0.010597401785069032f, w[7], s);
    return s;
}

// GLOBAL window load: 16 floats x[8q-8 .. 8q+7]; q==0 reflect path.
__device__ __forceinline__ void loadw16g(const float* __restrict__ src, int q, float* w) {
    if (q == 0) {
#pragma unroll
        for (int i = 0; i < 16; ++i) { int m = i - 8; m = (m < 0) ? -m : m; w[i] = src[m]; }
    } else {
        const float4 v0 = *(const float4*)(src + 8 * q - 8);
        const float4 v1 = *(const float4*)(src + 8 * q - 4);
        const float4 v2 = *(const float4*)(src + 8 * q);
        const float4 v3 = *(const float4*)(src + 8 * q + 4);
        w[0]  = v0.x; w[1]  = v0.y; w[2]  = v0.z; w[3]  = v0.w;
        w[4]  = v1.x; w[5]  = v1.y; w[6]  = v1.z; w[7]  = v1.w;
        w[8]  = v2.x; w[9]  = v2.y; w[10] = v2.z; w[11] = v2.w;
        w[12] = v3.x; w[13] = v3.y; w[14] = v3.z; w[15] = v3.w;
    }
}

// SWIZZLED LDS window load: 16 floats at region-relative offsets foff..foff+15
// (foff multiple of 4, >= 0). base = region origin (32-float aligned).
__device__ __forceinline__ void lw16s(const float* __restrict__ base, int foff, float* w) {
#pragma unroll
    for (int j = 0; j < 4; ++j) {
        const float4 v = *(const float4*)(base + swz4(foff + 4 * j));
        w[4*j+0] = v.x; w[4*j+1] = v.y; w[4*j+2] = v.z; w[4*j+3] = v.w;
    }
}
// Reflect path (global q==0, only where region shift is 0).
__device__ __forceinline__ void lw16s_q0(const float* __restrict__ base, float* w) {
#pragma unroll
    for (int i = 0; i < 16; ++i) { int m = i - 8; m = (m < 0) ? -m : m; w[i] = base[swz1(m)]; }
}

// NT store (builtin — correct vmcnt bookkeeping; +20% vs cached, r9/r11 A/B).
// Per-wave span of one instruction is contiguous (16B/lane) — r15 lesson.
__device__ __forceinline__ void ntst4(float* p, float a0, float a1, float a2, float a3) {
    f32x4 v; v.x = a0; v.y = a1; v.z = a2; v.w = a3;
    __builtin_nontemporal_store(v, (f32x4*)p);
}

// Barrier that waits on LDS ops only; outstanding NT stores drain in background.
__device__ __forceinline__ void barrier_lds() {
    asm volatile("s_waitcnt lgkmcnt(0)" ::: "memory");
    __builtin_amdgcn_s_barrier();
    asm volatile("" ::: "memory");
}

__global__ __launch_bounds__(256, 6)
void dwt5_kernel(const float* __restrict__ x, float* __restrict__ out)
{
    // Per-row region map (floats; origins 32-float aligned):
    //   a1: +0    [0 .. 2176)
    //   a2: +2176 [0 .. 1088)
    //   a3: +0    [0 .. 544)    (overwrites dead a1 after barrier)
    //   a4: +1024 [0 .. 272)
    // Row rr uses buf + rr*3264.
    __shared__ float buf[6528];   // 25.5 KB -> 6 blocks/CU
    const int bid = blockIdx.x;
    const int rp  = bid >> 2;     // row pair (rows 2rp, 2rp+1)
    const int h   = bid & 3;      // quarter
    const int tid = threadIdx.x;

    // Region shift per level (quarter h=0 has no halo).
    const int A1s = h ? 2048*h - 120 : 0;
    const int A2s = h ? 1024*h - 56  : 0;
    const int A3s = h ?  512*h - 24  : 0;
    const int A4s = h ?  256*h - 8   : 0;
    constexpr int REG2 = 2176;
    constexpr int REG4 = 1024;
    constexpr int ROWB = 3264;

    // ---- L1: x -> a1 (low only; d1 never output) ----
#pragma unroll
    for (int rr = 0; rr < 2; ++rr) {
        const int r = 2*rp + rr;
        const float* __restrict__ xr = x + (size_t)r * SLEN;
        float* const bb = buf + rr * ROWB;
        const int g1lo = A1s >> 2;            // 512h-30 | 0
        const int g1hi = 512 * (h + 1);
#pragma unroll
        for (int jj = 0; jj < 3; ++jj) {
            const int g = g1lo + tid + jj * 256;
            if (g < g1hi) {
                float w[16];
                loadw16g(xr, g, w);
                const float a0 = dotH(w + 1), a1 = dotH(w + 3), a2 = dotH(w + 5), a3 = dotH(w + 7);
                *(float4*)(bb + swz4(4 * g - A1s)) = make_float4(a0, a1, a2, a3);
            }
        }
    }
    barrier_lds();

    // ---- L2: a1 -> a2, d2 -> Fg + FR ----
#pragma unroll
    for (int rr = 0; rr < 2; ++rr) {
        const int r = 2*rp + rr;
        const size_t frBase = (size_t)33554432 + (size_t)r * 8192;
        float* const bb = buf + rr * ROWB;
        const int g2lo = A2s >> 2;            // 256h-14 | 0
        const int g2hi = 256 * (h + 1);
        const int gd   = 256 * h;
        float* __restrict__ hi1 = out + (size_t)16777216 + (size_t)r * 4096;
        float* __restrict__ hi2 = out + frBase + 4096;
#pragma unroll
        for (int jj = 0; jj < 2; ++jj) {
            const int g = g2lo + tid + jj * 256;
            if (g < g2hi) {
                float w[16];
                if (g == 0) lw16s_q0(bb, w);
                else        lw16s(bb, 8 * g - 8 - A1s, w);
                const float a0 = dotH(w + 1), a1 = dotH(w + 3), a2 = dotH(w + 5), a3 = dotH(w + 7);
                *(float4*)(bb + REG2 + swz4(4 * g - A2s)) = make_float4(a0, a1, a2, a3);
                if (g >= gd) {
                    const float d0 = dotG(w + 1), d1 = dotG(w + 3), d2 = dotG(w + 5), d3 = dotG(w + 7);
                    ntst4(hi1 + 4 * g, d0, d1, d2, d3);
                    ntst4(hi2 + 4 * g, d0, d1, d2, d3);
                }
            }
        }
    }
    barrier_lds();

    // ---- L3: a2 -> a3 (into dead a1 area), d3 -> Fb + FR ----
#pragma unroll
    for (int rr = 0; rr < 2; ++rr) {
        const int r = 2*rp + rr;
        const size_t frBase = (size_t)33554432 + (size_t)r * 8192;
        float* const bb = buf + rr * ROWB;
        const int g3lo = A3s >> 2;            // 128h-6 | 0
        const int g3hi = 128 * (h + 1);
        const int gd   = 128 * h;
        float* __restrict__ hi1 = out + (size_t)8388608 + (size_t)r * 2048;
        float* __restrict__ hi2 = out + frBase + 2048;
        const int g = g3lo + tid;
        if (g < g3hi) {
            float w[16];
            if (g == 0) lw16s_q0(bb + REG2, w);
            else        lw16s(bb + REG2, 8 * g - 8 - A2s, w);
            const float a0 = dotH(w + 1), a1 = dotH(w + 3), a2 = dotH(w + 5), a3 = dotH(w + 7);
            *(float4*)(bb + swz4(4 * g - A3s)) = make_float4(a0, a1, a2, a3);
            if (g >= gd) {
                const float d0 = dotG(w + 1), d1 = dotG(w + 3), d2 = dotG(w + 5), d3 = dotG(w + 7);
                ntst4(hi1 + 4 * g, d0, d1, d2, d3);
                ntst4(hi2 + 4 * g, d0, d1, d2, d3);
            }
        }
    }
    barrier_lds();

    // ---- L4: a3 -> a4, d4 -> Fa + FR ----
#pragma unroll
    for (int rr = 0; rr < 2; ++rr) {
        const int r = 2*rp + rr;
        const size_t frBase = (size_t)33554432 + (size_t)r * 8192;
        float* const bb = buf + rr * ROWB;
        const int g4lo = A4s >> 2;            // 64h-2 | 0
        const int g4hi = 64 * (h + 1);
        const int gd   = 64 * h;
        float* __restrict__ hi1 = out + (size_t)4194304 + (size_t)r * 1024;
        float* __restrict__ hi2 = out + frBase + 1024;
        const int g = g4lo + tid;
        if (g < g4hi) {
            float w[16];
            if (g == 0) lw16s_q0(bb, w);
            else        lw16s(bb, 8 * g - 8 - A3s, w);
            const float a0 = dotH(w + 1), a1 = dotH(w + 3), a2 = dotH(w + 5), a3 = dotH(w + 7);
            *(float4*)(bb + REG4 + swz4(4 * g - A4s)) = make_float4(a0, a1, a2, a3);
            if (g >= gd) {
                const float d0 = dotG(w + 1), d1 = dotG(w + 3), d2 = dotG(w + 5), d3 = dotG(w + 7);
                ntst4(hi1 + 4 * g, d0, d1, d2, d3);
                ntst4(hi2 + 4 * g, d0, d1, d2, d3);
            }
        }
    }
    barrier_lds();

    // ---- L5: a4 -> Fd + Ft, both also to FR ----
    if (tid < 64) {
        const int rr = tid >> 5;              // lanes 0-31: row0, 32-63: row1
        const int t  = tid & 31;
        const int r = 2*rp + rr;
        const size_t frBase = (size_t)33554432 + (size_t)r * 8192;
        float* const bb = buf + rr * ROWB;
        const int g = 32 * h + t;
        float w[16];
        if (g == 0) lw16s_q0(bb + REG4, w);
        else        lw16s(bb + REG4, 8 * g - 8 - A4s, w);
        const float a0 = dotH(w + 1), a1 = dotH(w + 3), a2 = dotH(w + 5), a3 = dotH(w + 7);
        const float d0 = dotG(w + 1), d1 = dotG(w + 3), d2 = dotG(w + 5), d3 = dotG(w + 7);
        ntst4(out + (size_t)r * 512 + 4 * g,                   a0, a1, a2, a3);
        ntst4(out + frBase + 4 * g,                            a0, a1, a2, a3);
        ntst4(out + (size_t)2097152 + (size_t)r * 512 + 4 * g, d0, d1, d2, d3);
        ntst4(out + frBase + 512 + 4 * g,                      d0, d1, d2, d3);
    }
}

extern "C" void kernel_launch(void* const* d_in, const int* in_sizes, int n_in,
                              void* d_out, int out_size, void* d_ws, size_t ws_size,
                              hipStream_t stream) {
    const float* x = (const float*)d_in[0];
    float* out = (float*)d_out;
    dwt5_kernel<<<8192, 256, 0, stream>>>(x, out);
}

// Round 17
// 84.004 us; speedup vs baseline: 1.1344x; 1.0834x over previous
//
#include <hip/hip_runtime.h>

// 5-level Db4 DWT, rows of 16384 fp32, B*C = 4096 rows.  CHAMPION (r12, 84.1us).
// Quarter-split rows (h = bid&3), telescoping halos a1:120/a2:56/a3:24/a4:8.
// x staged into LDS via global_load_lds width=16 (linear LDS dest,
// pre-swizzled global source — swizzle is an involution). XOR-swizzled LDS
// reads, LDS-only barriers (NT stores drain in background), builtin NT
// stores (+20% vs cached, r9/r11 A/B; must stay contiguous per wave, r15).
// out layout (flat, return order):
//   Fd  4096x512   @ 0
//   Ft  4096x512   @ 2097152
//   Fa  4096x1024  @ 4194304
//   Fb  4096x2048  @ 8388608
//   Fg  4096x4096  @ 16777216
//   FR  4096x8192  @ 33554432   (per-row: [Fd|Ft|Fa|Fb|Fg])

static constexpr int SLEN = 16384;

typedef float f32x4 __attribute__((ext_vector_type(4)));

// Swizzled float offset for a float4-aligned region-relative offset f (>=0).
__device__ __forceinline__ int swz4(int f) {
    const int s = f >> 2;
    return (s ^ ((s >> 3) & 7)) << 2;
}
__device__ __forceinline__ int swz1(int f) {
    const int s = f >> 2;
    return (((s ^ ((s >> 3) & 7)) << 2) | (f & 3));
}

// Db4 filters are fixed (non-learnable) — hardcoded as literals.
__device__ __forceinline__ float dotH(const float* w) {
    float s =      -0.010597401785069032f * w[0];
    s = fmaf( 0.032883011666982945f, w[1], s);
    s = fmaf( 0.030841381835560764f, w[2], s);
    s = fmaf(-0.18703481171888114f,  w[3], s);
    s = fmaf(-0.02798376941698385f,  w[4], s);
    s = fmaf( 0.6308807679295904f,   w[5], s);
    s = fmaf( 0.7148465705529155f,   w[6], s);
    s = fmaf( 0.2303778133088964f,   w[7], s);
    return s;
}
// g[k] = (-1)^k * h[7-k]
__device__ __forceinline__ float dotG(const float* w) {
    float s =       0.2303778133088964f * w[0];
    s = fmaf(-0.7148465705529155f,   w[1], s);
    s = fmaf( 0.6308807679295904f,   w[2], s);
    s = fmaf( 0.02798376941698385f,  w[3], s);
    s = fmaf(-0.18703481171888114f,  w[4], s);
    s = fmaf(-0.030841381835560764f, w[5], s);
    s = fmaf( 0.032883011666982945f, w[6], s);
    s = fmaf( 0.010597401785069032f, w[7], s);
    return s;
}

// SWIZZLED LDS window load: 16 floats at region-relative offsets foff..foff+15
// (foff multiple of 4, >= 0). base = region origin (32-float aligned).
__device__ __forceinline__ void lw16s(const float* __restrict__ base, int foff, float* w) {
#pragma unroll
    for (int j = 0; j < 4; ++j) {
        const float4 v = *(const float4*)(base + swz4(foff + 4 * j));
        w[4*j+0] = v.x; w[4*j+1] = v.y; w[4*j+2] = v.z; w[4*j+3] = v.w;
    }
}
// Reflect path (global q==0, only where region shift is 0).
__device__ __forceinline__ void lw16s_q0(const float* __restrict__ base, float* w) {
#pragma unroll
    for (int i = 0; i < 16; ++i) { int m = i - 8; m = (m < 0) ? -m : m; w[i] = base[swz1(m)]; }
}

// NT store (builtin — correct vmcnt bookkeeping; +20% vs cached, r9/r11 A/B).
__device__ __forceinline__ void ntst4(float* p, float a0, float a1, float a2, float a3) {
    f32x4 v; v.x = a0; v.y = a1; v.z = a2; v.w = a3;
    __builtin_nontemporal_store(v, (f32x4*)p);
}

// Async global->LDS, 16B per lane.
__device__ __forceinline__ void gl_lds16(const float* gp, float* lp) {
    __builtin_amdgcn_global_load_lds(
        (const __attribute__((address_space(1))) void*)gp,
        (__attribute__((address_space(3))) void*)lp, 16, 0, 0);
}

// Barrier that waits on LDS ops only; outstanding NT stores drain in background.
__device__ __forceinline__ void barrier_lds() {
    asm volatile("s_waitcnt lgkmcnt(0)" ::: "memory");
    __builtin_amdgcn_s_barrier();
    asm volatile("" ::: "memory");
}

__global__ __launch_bounds__(256, 6)
void dwt5_kernel(const float* __restrict__ x, float* __restrict__ out)
{
    // Region map (floats; bases multiples of 32 floats):
    //   xs: buf+0    [0 .. 4352)  staged x (linear dest, pre-swizzled source)
    //   a1: buf+4352 [0 .. 2176)
    //   a2: buf+0    [0 .. 1088)  (xs dead after L1 barrier)
    //   a3: buf+2048 [0 .. 544)
    //   a4: buf+3072 [0 .. 272)
    __shared__ float buf[6528];   // 25.5 KB -> 6 blocks/CU
    const int bid = blockIdx.x;
    const int r   = bid >> 2;     // row
    const int h   = bid & 3;      // quarter
    const int tid = threadIdx.x;

    const float* __restrict__ xr = x + (size_t)r * SLEN;
    const size_t frBase = (size_t)33554432 + (size_t)r * 8192;

    // Region shift per level (quarter h=0 has no halo).
    const int X0  = h ? 4096*h - 256 : 0;    // xs global float start
    const int A1s = h ? 2048*h - 120 : 0;
    const int A2s = h ? 1024*h - 56  : 0;
    const int A3s = h ?  512*h - 24  : 0;
    const int A4s = h ?  256*h - 8   : 0;
    constexpr int RA1 = 4352;
    constexpr int RA2 = 0;
    constexpr int RA3 = 2048;
    constexpr int RA4 = 3072;

    // ---- STAGE: x -> xs (linear LDS; source pre-swizzled so reads can swz) ----
    {
        const float* xsrc = xr + X0;
#pragma unroll
        for (int j = 0; j < 4; ++j) {
            const int L  = tid + 256*j;            // linear LDS slot
            const int Ls = L ^ ((L >> 3) & 7);     // source slot (involution)
            gl_lds16(xsrc + 4*Ls, buf + 4*L);
        }
        if (h != 0 && tid < 64) {                  // slots 1024..1087 (halo)
            const int L  = tid + 1024;
            const int Ls = L ^ ((L >> 3) & 7);
            gl_lds16(xsrc + 4*Ls, buf + 4*L);
        }
        asm volatile("s_waitcnt vmcnt(0)" ::: "memory");
    }
    barrier_lds();

    // ---- L1: xs -> a1 (low only; d1 never output) ----
    {
        const int g1lo = A1s >> 2;            // 512h-30 | 0
        const int g1hi = 512 * (h + 1);
#pragma unroll
        for (int jj = 0; jj < 3; ++jj) {
            const int g = g1lo + tid + jj * 256;
            if (g < g1hi) {
                float w[16];
                if (g == 0) lw16s_q0(buf, w);
                else        lw16s(buf, 8 * g - 8 - X0, w);
                const float a0 = dotH(w + 1), a1 = dotH(w + 3), a2 = dotH(w + 5), a3 = dotH(w + 7);
                *(float4*)(buf + RA1 + swz4(4 * g - A1s)) = make_float4(a0, a1, a2, a3);
            }
        }
    }
    barrier_lds();

    // ---- L2: a1 -> a2, d2 -> Fg + FR ----
    {
        const int g2lo = A2s >> 2;            // 256h-14 | 0
        const int g2hi = 256 * (h + 1);
        const int gd   = 256 * h;
        float* __restrict__ hi1 = out + (size_t)16777216 + (size_t)r * 4096;
        float* __restrict__ hi2 = out + frBase + 4096;
#pragma unroll
        for (int jj = 0; jj < 2; ++jj) {
            const int g = g2lo + tid + jj * 256;
            if (g < g2hi) {
                float w[16];
                if (g == 0) lw16s_q0(buf + RA1, w);
                else        lw16s(buf + RA1, 8 * g - 8 - A1s, w);
                const float a0 = dotH(w + 1), a1 = dotH(w + 3), a2 = dotH(w + 5), a3 = dotH(w + 7);
                *(float4*)(buf + RA2 + swz4(4 * g - A2s)) = make_float4(a0, a1, a2, a3);
                if (g >= gd) {
                    const float d0 = dotG(w + 1), d1 = dotG(w + 3), d2 = dotG(w + 5), d3 = dotG(w + 7);
                    ntst4(hi1 + 4 * g, d0, d1, d2, d3);
                    ntst4(hi2 + 4 * g, d0, d1, d2, d3);
                }
            }
        }
    }
    barrier_lds();

    // ---- L3: a2 -> a3, d3 -> Fb + FR ----
    {
        const int g3lo = A3s >> 2;            // 128h-6 | 0
        const int g3hi = 128 * (h + 1);
        const int gd   = 128 * h;
        float* __restrict__ hi1 = out + (size_t)8388608 + (size_t)r * 2048;
        float* __restrict__ hi2 = out + frBase + 2048;
        const int g = g3lo + tid;
        if (g < g3hi) {
            float w[16];
            if (g == 0) lw16s_q0(buf + RA2, w);
            else        lw16s(buf + RA2, 8 * g - 8 - A2s, w);
            const float a0 = dotH(w + 1), a1 = dotH(w + 3), a2 = dotH(w + 5), a3 = dotH(w + 7);
            *(float4*)(buf + RA3 + swz4(4 * g - A3s)) = make_float4(a0, a1, a2, a3);
            if (g >= gd) {
                const float d0 = dotG(w + 1), d1 = dotG(w + 3), d2 = dotG(w + 5), d3 = dotG(w + 7);
                ntst4(hi1 + 4 * g, d0, d1, d2, d3);
                ntst4(hi2 + 4 * g, d0, d1, d2, d3);
            }
        }
    }
    barrier_lds();

    // ---- L4: a3 -> a4, d4 -> Fa + FR ----
    {
        const int g4lo = A4s >> 2;            // 64h-2 | 0
        const int g4hi = 64 * (h + 1);
        const int gd   = 64 * h;
        float* __restrict__ hi1 = out + (size_t)4194304 + (size_t)r * 1024;
        float* __restrict__ hi2 = out + frBase + 1024;
        const int g = g4lo + tid;
        if (g < g4hi) {
            float w[16];
            if (g == 0) lw16s_q0(buf + RA3, w);
            else        lw16s(buf + RA3, 8 * g - 8 - A3s, w);
            const float a0 = dotH(w + 1), a1 = dotH(w + 3), a2 = dotH(w + 5), a3 = dotH(w + 7);
            *(float4*)(buf + RA4 + swz4(4 * g - A4s)) = make_float4(a0, a1, a2, a3);
            if (g >= gd) {
                const float d0 = dotG(w + 1), d1 = dotG(w + 3), d2 = dotG(w + 5), d3 = dotG(w + 7);
                ntst4(hi1 + 4 * g, d0, d1, d2, d3);
                ntst4(hi2 + 4 * g, d0, d1, d2, d3);
            }
        }
    }
    barrier_lds();

    // ---- L5: a4 -> Fd + Ft, both also to FR ----
    if (tid < 32) {
        const int g = 32 * h + tid;
        float w[16];
        if (g == 0) lw16s_q0(buf + RA4, w);
        else        lw16s(buf + RA4, 8 * g - 8 - A4s, w);
        const float a0 = dotH(w + 1), a1 = dotH(w + 3), a2 = dotH(w + 5), a3 = dotH(w + 7);
        const float d0 = dotG(w + 1), d1 = dotG(w + 3), d2 = dotG(w + 5), d3 = dotG(w + 7);
        ntst4(out + (size_t)r * 512 + 4 * g,                   a0, a1, a2, a3);
        ntst4(out + frBase + 4 * g,                            a0, a1, a2, a3);
        ntst4(out + (size_t)2097152 + (size_t)r * 512 + 4 * g, d0, d1, d2, d3);
        ntst4(out + frBase + 512 + 4 * g,                      d0, d1, d2, d3);
    }
}

extern "C" void kernel_launch(void* const* d_in, const int* in_sizes, int n_in,
                              void* d_out, int out_size, void* d_ws, size_t ws_size,
                              hipStream_t stream) {
    const float* x = (const float*)d_in[0];
    float* out = (float*)d_out;
    dwt5_kernel<<<16384, 256, 0, stream>>>(x, out);
}